// Round 10
// baseline (148.217 us; speedup 1.0000x reference)
//
#include <hip/hip_runtime.h>
#include <hip/hip_bf16.h>

constexpr int B_ = 32, C_ = 256, H_ = 32, W_ = 32, M_ = 1024;
constexpr int NH = 4, DK = 16, DV = 64;
constexpr float EPS = 1e-5f;

__device__ __forceinline__ float bf2f(ushort u) {
    return __uint_as_float(((unsigned)u) << 16);
}

// ---------------- Kernel 1: qkv = W(144x256) @ x(256xM) per batch, + BN ----
// ci-step-4 register tiling: 13 b128 LDS reads per 4 ci (was ~40 scalar),
// wsh padded to 68 so the 4 row-addrs/wave hit disjoint banks.
__global__ __launch_bounds__(256) void k_qkv(
    const float* __restrict__ x, const float* __restrict__ w,
    const float* __restrict__ qg, const float* __restrict__ qb,
    const float* __restrict__ qm, const float* __restrict__ qv,
    const float* __restrict__ vg, const float* __restrict__ vb,
    const float* __restrict__ vm, const float* __restrict__ vv,
    float* __restrict__ q_out, float* __restrict__ k_out,
    float* __restrict__ v_out)
{
    __shared__ float xs[64][64];    // 16 KB
    __shared__ float wsh[144][68];  // 38.3 KB (pad 68: bank-spread rows)
    const int b   = blockIdx.x >> 4;
    const int m0  = (blockIdx.x & 15) * 64;
    const int tid = threadIdx.x;
    const int ml  = tid & 15;
    const int og  = tid >> 4;

    float acc[4][9];
#pragma unroll
    for (int i = 0; i < 4; i++)
#pragma unroll
        for (int j = 0; j < 9; j++) acc[i][j] = 0.f;

    for (int c0 = 0; c0 < C_; c0 += 64) {
        __syncthreads();
#pragma unroll
        for (int i = 0; i < 4; i++) {            // 4096 x = 1024 float4
            int f4 = tid + 256 * i;
            int ci = f4 >> 4, mf = (f4 & 15) * 4;
            *reinterpret_cast<float4*>(&xs[ci][mf]) =
                *reinterpret_cast<const float4*>(&x[(b * C_ + c0 + ci) * M_ + m0 + mf]);
        }
#pragma unroll
        for (int i = 0; i < 9; i++) {            // 9216 w = 2304 float4
            int f4 = tid + 256 * i;
            int o = f4 >> 4, cf = (f4 & 15) * 4;
            *reinterpret_cast<float4*>(&wsh[o][cf]) =
                *reinterpret_cast<const float4*>(&w[o * C_ + c0 + cf]);
        }
        __syncthreads();
#pragma unroll 1
        for (int ci = 0; ci < 64; ci += 4) {
            float4 xv0 = *reinterpret_cast<const float4*>(&xs[ci + 0][ml * 4]);
            float4 xv1 = *reinterpret_cast<const float4*>(&xs[ci + 1][ml * 4]);
            float4 xv2 = *reinterpret_cast<const float4*>(&xs[ci + 2][ml * 4]);
            float4 xv3 = *reinterpret_cast<const float4*>(&xs[ci + 3][ml * 4]);
            float4 wv[9];
#pragma unroll
            for (int j = 0; j < 9; j++)
                wv[j] = *reinterpret_cast<const float4*>(&wsh[og + 16 * j][ci]);
#pragma unroll
            for (int j = 0; j < 9; j++) {
                acc[0][j] = fmaf(wv[j].x, xv0.x, acc[0][j]);
                acc[0][j] = fmaf(wv[j].y, xv1.x, acc[0][j]);
                acc[0][j] = fmaf(wv[j].z, xv2.x, acc[0][j]);
                acc[0][j] = fmaf(wv[j].w, xv3.x, acc[0][j]);
                acc[1][j] = fmaf(wv[j].x, xv0.y, acc[1][j]);
                acc[1][j] = fmaf(wv[j].y, xv1.y, acc[1][j]);
                acc[1][j] = fmaf(wv[j].z, xv2.y, acc[1][j]);
                acc[1][j] = fmaf(wv[j].w, xv3.y, acc[1][j]);
                acc[2][j] = fmaf(wv[j].x, xv0.z, acc[2][j]);
                acc[2][j] = fmaf(wv[j].y, xv1.z, acc[2][j]);
                acc[2][j] = fmaf(wv[j].z, xv2.z, acc[2][j]);
                acc[2][j] = fmaf(wv[j].w, xv3.z, acc[2][j]);
                acc[3][j] = fmaf(wv[j].x, xv0.w, acc[3][j]);
                acc[3][j] = fmaf(wv[j].y, xv1.w, acc[3][j]);
                acc[3][j] = fmaf(wv[j].z, xv2.w, acc[3][j]);
                acc[3][j] = fmaf(wv[j].w, xv3.w, acc[3][j]);
            }
        }
    }

    const int mbase = m0 + ml * 4;
#pragma unroll
    for (int j = 0; j < 9; j++) {
        const int o = og + 16 * j;
        if (o < 64) {                         // q channel: BN then [b][m][n][k]
            float inv = qg[o] * rsqrtf(qv[o] + EPS);
            float add = qb[o] - qm[o] * inv;
            int n = o >> 4, k = o & 15;
#pragma unroll
            for (int i = 0; i < 4; i++)
                q_out[((b * M_ + mbase + i) * NH + n) * DK + k] =
                    acc[i][j] * inv + add;
        } else if (o < 80) {                  // k logits: [b][k][m]
            int kk = o - 64;
#pragma unroll
            for (int i = 0; i < 4; i++)
                k_out[(b * DK + kk) * M_ + mbase + i] = acc[i][j];
        } else {                              // v channel: BN then [b][m][vd]
            int vd = o - 80;
            float inv = vg[vd] * rsqrtf(vv[vd] + EPS);
            float add = vb[vd] - vm[vd] * inv;
#pragma unroll
            for (int i = 0; i < 4; i++)
                v_out[(b * M_ + mbase + i) * DV + vd] = acc[i][j] * inv + add;
        }
    }
}

// ---------------- Kernel 2: softmax over M per (b,k) row, in place ---------
__global__ __launch_bounds__(256) void k_softmax(float* __restrict__ kl)
{
    float* p = kl + (size_t)blockIdx.x * M_;
    const int tid = threadIdx.x;
    float v[4];
    float mx = -1e30f;
#pragma unroll
    for (int i = 0; i < 4; i++) { v[i] = p[tid + 256 * i]; mx = fmaxf(mx, v[i]); }
#pragma unroll
    for (int off = 32; off >= 1; off >>= 1) mx = fmaxf(mx, __shfl_xor(mx, off));
    __shared__ float red[8];
    if ((tid & 63) == 0) red[tid >> 6] = mx;
    __syncthreads();
    mx = fmaxf(fmaxf(red[0], red[1]), fmaxf(red[2], red[3]));
    float s = 0.f;
#pragma unroll
    for (int i = 0; i < 4; i++) { v[i] = __expf(v[i] - mx); s += v[i]; }
#pragma unroll
    for (int off = 32; off >= 1; off >>= 1) s += __shfl_xor(s, off);
    if ((tid & 63) == 0) red[4 + (tid >> 6)] = s;
    __syncthreads();
    s = red[4] + red[5] + red[6] + red[7];
    float inv = 1.f / s;
#pragma unroll
    for (int i = 0; i < 4; i++) p[tid + 256 * i] = v[i] * inv;
}

// ---------------- Kernel 3: content_lam[b,k,vd] = sum_m ksm * v ------------
__global__ __launch_bounds__(256) void k_clam(
    const float* __restrict__ ksm, const float* __restrict__ vbn,
    float* __restrict__ clam)
{
    const int b   = blockIdx.x >> 3;
    const int m0  = (blockIdx.x & 7) * 128;
    const int tid = threadIdx.x;
    const int vd  = tid & 63;
    const int kq  = tid >> 6;
    float acc[4] = {0.f, 0.f, 0.f, 0.f};
    for (int mi = 0; mi < 128; mi++) {
        const int m = m0 + mi;
        const float vvv = vbn[(b * M_ + m) * DV + vd];
#pragma unroll
        for (int j = 0; j < 4; j++)
            acc[j] = fmaf(ksm[(b * DK + kq + 4 * j) * M_ + m], vvv, acc[j]);
    }
#pragma unroll
    for (int j = 0; j < 4; j++)
        atomicAdd(&clam[(b * DK + kq + 4 * j) * DV + vd], acc[j]);
}

// ---------------- Kernel 4: fused 7x7 conv (pos_lam) + final matmul --------
// Round-9 structure, LDS squeezed under 80 KB for 2 blocks/CU:
//   v halo in bf16 (8 rows, 32 KB), ostage[64][128] XOR-swizzled (32 KB,
//   per-row flush), lw_t/cl_s ~7 KB  => ~73 KB total, grid 512 = 2 blk/CU.
// 512 thr: vd=tid&63, pg=tid>>6 (4 px).  2-row tiles, grp in {0,1}.
__global__ __launch_bounds__(512) void k_fuse(
    const float* __restrict__ vbn, const float* __restrict__ qbn,
    const float* __restrict__ clam,
    const float* __restrict__ lw, const float* __restrict__ lb,
    float* __restrict__ out)
{
    __shared__ ushort v_sh[8 * 32 * 64];   // 32 KB bf16: rows h0-3 .. h0+4
    __shared__ float ostage[64][128];      // 32 KB, col ^= (vd&7)<<2 swizzle
    __shared__ float lw_t[49 * 16];        // 3.1 KB, [tap][k]
    __shared__ float cl_s[16 * 64];        // 4 KB
    __shared__ float lb_s[16];

    const int b   = blockIdx.x >> 4;
    const int rt  = blockIdx.x & 15;
    const int h0  = rt * 2;
    const int tid = threadIdx.x;

    for (int i4 = tid; i4 < 4096; i4 += 512) {   // 16384 bf16 = 4096 ushort4
        int r   = i4 >> 9;                 // staged row 0..7 = global h0-3+r
        int rem = (i4 & 511) * 4;
        int gr  = h0 - 3 + r;
        float4 val = make_float4(0.f, 0.f, 0.f, 0.f);
        if (gr >= 0 && gr < H_)
            val = *reinterpret_cast<const float4*>(&vbn[(b * M_ + gr * W_) * DV + rem]);
        ushort4 u;
        u.x = __bfloat16_as_ushort(__float2bfloat16(val.x));
        u.y = __bfloat16_as_ushort(__float2bfloat16(val.y));
        u.z = __bfloat16_as_ushort(__float2bfloat16(val.z));
        u.w = __bfloat16_as_ushort(__float2bfloat16(val.w));
        *reinterpret_cast<ushort4*>(&v_sh[r * 2048 + rem]) = u;
    }
    for (int i = tid; i < 784; i += 512) {       // transpose: [k][tap]->[tap][k]
        int tap = i >> 4, k = i & 15;
        lw_t[i] = lw[k * 49 + tap];
    }
    if (tid < 256)
        *reinterpret_cast<float4*>(&cl_s[tid * 4]) =
            *reinterpret_cast<const float4*>(&clam[b * DK * DV + tid * 4]);
    if (tid < 16) lb_s[tid] = lb[tid];
    __syncthreads();

    const int vd  = tid & 63;
    const int pg  = tid >> 6;       // wave index: pixel column group
    const int px0 = pg * 4;
    const int swz = (vd & 7) << 2;

    for (int grp = 0; grp < 2; grp++) {     // output row h0+grp
        float plam[4][16];
#pragma unroll
        for (int ip = 0; ip < 4; ip++)
#pragma unroll
            for (int k = 0; k < 16; k++) plam[ip][k] = 0.f;

#pragma unroll 1
        for (int dy = 0; dy < 7; dy++) {
            const int rbase = (grp + dy) * W_;   // staged row index * 32
            float vr[10];                        // cols px0-3 .. px0+6
#pragma unroll
            for (int j = 0; j < 10; j++) {
                const int col = px0 - 3 + j;     // wave-uniform validity
                vr[j] = (col >= 0 && col < W_)
                      ? bf2f(v_sh[(rbase + col) * DV + vd]) : 0.f;
            }
#pragma unroll
            for (int dx = 0; dx < 7; dx++) {
                const float* lwp = &lw_t[(dy * 7 + dx) * 16];
                float4 l0 = *reinterpret_cast<const float4*>(lwp);
                float4 l1 = *reinterpret_cast<const float4*>(lwp + 4);
                float4 l2 = *reinterpret_cast<const float4*>(lwp + 8);
                float4 l3 = *reinterpret_cast<const float4*>(lwp + 12);
                const float lwv[16] = {l0.x, l0.y, l0.z, l0.w, l1.x, l1.y, l1.z, l1.w,
                                       l2.x, l2.y, l2.z, l2.w, l3.x, l3.y, l3.z, l3.w};
#pragma unroll
                for (int ip = 0; ip < 4; ip++) {
                    const float vvv = vr[ip + dx];
#pragma unroll
                    for (int k = 0; k < 16; k++)
                        plam[ip][k] = fmaf(vvv, lwv[k], plam[ip][k]);
                }
            }
        }
        // epilogue: 4 pixels of this row -> ostage (swizzled)
        const int mrow = (h0 + grp) * W_;
#pragma unroll
        for (int ip = 0; ip < 4; ip++) {
            const int p = px0 + ip;              // 0..31 within row
            const int m = mrow + p;
            float lamv[16];
#pragma unroll
            for (int k = 0; k < 16; k++)
                lamv[k] = plam[ip][k] + cl_s[k * DV + vd] + lb_s[k];
            const float* qp = qbn + (size_t)(b * M_ + m) * NH * DK;
            float4 ov;
            float* ovp = reinterpret_cast<float*>(&ov);
#pragma unroll
            for (int n = 0; n < 4; n++) {
                const float4* q4 = reinterpret_cast<const float4*>(qp + n * DK);
                float4 qa = q4[0], qb4 = q4[1], qc = q4[2], qd = q4[3];
                ovp[n] = qa.x * lamv[0] + qa.y * lamv[1] + qa.z * lamv[2] + qa.w * lamv[3]
                       + qb4.x * lamv[4] + qb4.y * lamv[5] + qb4.z * lamv[6] + qb4.w * lamv[7]
                       + qc.x * lamv[8] + qc.y * lamv[9] + qc.z * lamv[10] + qc.w * lamv[11]
                       + qd.x * lamv[12] + qd.y * lamv[13] + qd.z * lamv[14] + qd.w * lamv[15];
            }
            *reinterpret_cast<float4*>(&ostage[vd][(p * 4) ^ swz]) = ov;
        }
        __syncthreads();
        // flush this row: 2048 float4, lanes consecutive -> coalesced
        {
            const int mrow4 = mrow * 4;
            for (int i4 = tid; i4 < 2048; i4 += 512) {
                const int vdw  = i4 >> 5;          // 32 float4 per vd
                const int off4 = (i4 & 31) * 4;
                float4 val = *reinterpret_cast<const float4*>(
                    &ostage[vdw][off4 ^ ((vdw & 7) << 2)]);
                *reinterpret_cast<float4*>(
                    out + (size_t)b * (C_ * M_) + (size_t)vdw * 4096 + mrow4 + off4) = val;
            }
        }
        __syncthreads();
    }
}

extern "C" void kernel_launch(void* const* d_in, const int* in_sizes, int n_in,
                              void* d_out, int out_size, void* d_ws, size_t ws_size,
                              hipStream_t stream)
{
    (void)in_sizes; (void)n_in; (void)out_size; (void)ws_size;
    const float* x   = (const float*)d_in[0];
    const float* w   = (const float*)d_in[1];
    const float* qg  = (const float*)d_in[2];
    const float* qb  = (const float*)d_in[3];
    const float* qm  = (const float*)d_in[4];
    const float* qvr = (const float*)d_in[5];
    const float* vg  = (const float*)d_in[6];
    const float* vb  = (const float*)d_in[7];
    const float* vm  = (const float*)d_in[8];
    const float* vvr = (const float*)d_in[9];
    const float* lw  = (const float*)d_in[10];
    const float* lb  = (const float*)d_in[11];
    float* out = (float*)d_out;

    float* ws   = (float*)d_ws;
    float* q_bn = ws;                  // [b][m][n][k]  2,097,152 f
    float* v_bn = ws + 2097152;        // [b][m][vd]    2,097,152 f
    float* k_bf = ws + 4194304;        // [b][k][m]       524,288 f (in-place sm)
    float* clam = ws + 4718592;        // [b][k][vd]       32,768 f

    hipMemsetAsync(clam, 0, 32768 * sizeof(float), stream);
    hipLaunchKernelGGL(k_qkv, dim3(512), dim3(256), 0, stream,
                       x, w, qg, qb, qm, qvr, vg, vb, vm, vvr, q_bn, k_bf, v_bn);
    hipLaunchKernelGGL(k_softmax, dim3(512), dim3(256), 0, stream, k_bf);
    hipLaunchKernelGGL(k_clam, dim3(256), dim3(256), 0, stream, k_bf, v_bn, clam);
    hipLaunchKernelGGL(k_fuse, dim3(512), dim3(512), 0, stream,
                       v_bn, q_bn, clam, lw, lb, out);
}

// Round 11
// 107.642 us; speedup vs baseline: 1.3769x; 1.3769x over previous
//
#include <hip/hip_runtime.h>
#include <hip/hip_bf16.h>

constexpr int B_ = 32, C_ = 256, H_ = 32, W_ = 32, M_ = 1024;
constexpr int NH = 4, DK = 16, DV = 64;
constexpr float EPS = 1e-5f;

using bf16x8 = __bf16 __attribute__((ext_vector_type(8)));
using f32x4  = float __attribute__((ext_vector_type(4)));

struct alignas(8) Bf4 { __bf16 a, b, c, d; };

// ---------------- Kernel 0: W fp32 -> bf16 (once; 36864 elems) -------------
__global__ __launch_bounds__(256) void k_wbf(
    const float* __restrict__ w, __bf16* __restrict__ wbf)
{
    int i = blockIdx.x * 256 + threadIdx.x;          // 9216 float4s
    if (i < 9216) {
        float4 f = reinterpret_cast<const float4*>(w)[i];
        Bf4 o{(__bf16)f.x, (__bf16)f.y, (__bf16)f.z, (__bf16)f.w};
        *reinterpret_cast<Bf4*>(&wbf[i * 4]) = o;
    }
}

// ---------------- Kernel 1: qkv = W @ x via bf16 MFMA, + BN ----------------
// grid 32 b x 16 m-tiles(64).  256 thr = 4 waves; wave w owns m-sub
// [16w,16w+16), all 9 o-tiles (q:0-3, k:4, v:5-8), K = 8 steps of 32.
// A-frags direct from global wbf (L2-resident): lane o=l&15, c=(l>>4)*8.
// B-frags from LDS xT[64 m][72 c] bf16 (transposed+cvt during staging).
// Epilogue: ostage[64][68] fp32 transpose passes (q,k,v), BN in flush.
__global__ __launch_bounds__(256) void k_qkv(
    const float* __restrict__ x, const __bf16* __restrict__ wbf,
    const float* __restrict__ qg, const float* __restrict__ qb,
    const float* __restrict__ qm, const float* __restrict__ qv,
    const float* __restrict__ vg, const float* __restrict__ vb,
    const float* __restrict__ vm, const float* __restrict__ vv,
    float* __restrict__ q_out, float* __restrict__ k_out,
    float* __restrict__ v_out)
{
    __shared__ __bf16 xT[64 * 72];                 // 9 KB
    __shared__ __align__(16) float ostage[64 * 68]; // 17 KB (reused per pass)
    __shared__ __align__(16) float inv_s[144];
    __shared__ __align__(16) float add_s[144];

    const int b    = blockIdx.x >> 4;
    const int m0   = (blockIdx.x & 15) * 64;
    const int tid  = threadIdx.x;
    const int wv   = tid >> 6;
    const int lane = tid & 63;
    const int col  = lane & 15;        // m-local within wave sub / D col
    const int rowg = lane >> 4;        // D row group

    if (tid < 144) {                   // BN params (identity for k rows)
        float iv = 1.f, ad = 0.f;
        if (tid < 64)       { iv = qg[tid] * rsqrtf(qv[tid] + EPS); ad = qb[tid] - qm[tid] * iv; }
        else if (tid >= 80) { int d = tid - 80; iv = vg[d] * rsqrtf(vv[d] + EPS); ad = vb[d] - vm[d] * iv; }
        inv_s[tid] = iv; add_s[tid] = ad;
    }

    f32x4 acc[9];
#pragma unroll
    for (int j = 0; j < 9; j++) acc[j] = (f32x4){0.f, 0.f, 0.f, 0.f};

    for (int c0 = 0; c0 < C_; c0 += 64) {
        __syncthreads();
        // stage xT[m][c] bf16: 64m x 64c, pack 4 c per b64 write
#pragma unroll
        for (int i = 0; i < 4; i++) {
            int flat = tid + 256 * i;              // 0..1023
            int m = flat & 63, c4 = flat >> 6;     // c4: 0..15
            const float* xp = &x[((size_t)b * C_ + c0 + c4 * 4) * M_ + m0 + m];
            float f0 = xp[0], f1 = xp[M_], f2 = xp[2 * M_], f3 = xp[3 * M_];
            Bf4 o{(__bf16)f0, (__bf16)f1, (__bf16)f2, (__bf16)f3};
            *reinterpret_cast<Bf4*>(&xT[m * 72 + c4 * 4]) = o;
        }
        __syncthreads();
#pragma unroll
        for (int ks = 0; ks < 2; ks++) {
            const int cl = ks * 32 + rowg * 8;
            bf16x8 bf = *reinterpret_cast<const bf16x8*>(
                &xT[(16 * wv + col) * 72 + cl]);
#pragma unroll
            for (int j = 0; j < 9; j++) {
                bf16x8 af = *reinterpret_cast<const bf16x8*>(
                    &wbf[(size_t)(16 * j + col) * C_ + c0 + cl]);
                acc[j] = __builtin_amdgcn_mfma_f32_16x16x32_bf16(af, bf, acc[j], 0, 0, 0);
            }
        }
    }

    // ---------------- epilogue: 3 transpose passes ----------------
    const int mloc = 16 * wv + col;    // 0..63

    // pass Q: o-tiles 0..3 -> ostage[m][o], flush with BN -> q_out[b][m][64]
    __syncthreads();
#pragma unroll
    for (int j = 0; j < 4; j++)
        *reinterpret_cast<f32x4*>(&ostage[mloc * 68 + 16 * j + rowg * 4]) = acc[j];
    __syncthreads();
#pragma unroll
    for (int i = 0; i < 4; i++) {
        int fl = tid + 256 * i;                    // 1024 float4s
        int m = fl >> 4, oc4 = (fl & 15) * 4;
        float4 vr = *reinterpret_cast<const float4*>(&ostage[m * 68 + oc4]);
        float4 iv = *reinterpret_cast<const float4*>(&inv_s[oc4]);
        float4 ad = *reinterpret_cast<const float4*>(&add_s[oc4]);
        float4 rs{vr.x * iv.x + ad.x, vr.y * iv.y + ad.y,
                  vr.z * iv.z + ad.z, vr.w * iv.w + ad.w};
        *reinterpret_cast<float4*>(&q_out[((size_t)b * M_ + m0 + m) * 64 + oc4]) = rs;
    }

    // pass K: o-tile 4 -> ostage[k][m], flush raw -> k_out[b][k][m]
    __syncthreads();
#pragma unroll
    for (int r = 0; r < 4; r++)
        ostage[(rowg * 4 + r) * 68 + mloc] = acc[4][r];
    __syncthreads();
    {
        int kk = tid >> 4, m4 = (tid & 15) * 4;    // 256 float4s
        float4 vr = *reinterpret_cast<const float4*>(&ostage[kk * 68 + m4]);
        *reinterpret_cast<float4*>(&k_out[((size_t)b * DK + kk) * M_ + m0 + m4]) = vr;
    }

    // pass V: o-tiles 5..8 -> ostage[m][vd], flush with BN -> v_out[b][m][64]
    __syncthreads();
#pragma unroll
    for (int j = 5; j < 9; j++)
        *reinterpret_cast<f32x4*>(&ostage[mloc * 68 + 16 * (j - 5) + rowg * 4]) = acc[j];
    __syncthreads();
#pragma unroll
    for (int i = 0; i < 4; i++) {
        int fl = tid + 256 * i;
        int m = fl >> 4, oc4 = (fl & 15) * 4;
        float4 vr = *reinterpret_cast<const float4*>(&ostage[m * 68 + oc4]);
        float4 iv = *reinterpret_cast<const float4*>(&inv_s[80 + oc4]);
        float4 ad = *reinterpret_cast<const float4*>(&add_s[80 + oc4]);
        float4 rs{vr.x * iv.x + ad.x, vr.y * iv.y + ad.y,
                  vr.z * iv.z + ad.z, vr.w * iv.w + ad.w};
        *reinterpret_cast<float4*>(&v_out[((size_t)b * M_ + m0 + m) * 64 + oc4]) = rs;
    }
}

// ---------------- Kernel 2: softmax over M per (b,k) row, in place ---------
__global__ __launch_bounds__(256) void k_softmax(float* __restrict__ kl)
{
    float* p = kl + (size_t)blockIdx.x * M_;
    const int tid = threadIdx.x;
    float v[4];
    float mx = -1e30f;
#pragma unroll
    for (int i = 0; i < 4; i++) { v[i] = p[tid + 256 * i]; mx = fmaxf(mx, v[i]); }
#pragma unroll
    for (int off = 32; off >= 1; off >>= 1) mx = fmaxf(mx, __shfl_xor(mx, off));
    __shared__ float red[8];
    if ((tid & 63) == 0) red[tid >> 6] = mx;
    __syncthreads();
    mx = fmaxf(fmaxf(red[0], red[1]), fmaxf(red[2], red[3]));
    float s = 0.f;
#pragma unroll
    for (int i = 0; i < 4; i++) { v[i] = __expf(v[i] - mx); s += v[i]; }
#pragma unroll
    for (int off = 32; off >= 1; off >>= 1) s += __shfl_xor(s, off);
    if ((tid & 63) == 0) red[4 + (tid >> 6)] = s;
    __syncthreads();
    s = red[4] + red[5] + red[6] + red[7];
    float inv = 1.f / s;
#pragma unroll
    for (int i = 0; i < 4; i++) p[tid + 256 * i] = v[i] * inv;
}

// ---------------- Kernel 3: content_lam[b,k,vd] = sum_m ksm * v ------------
__global__ __launch_bounds__(256) void k_clam(
    const float* __restrict__ ksm, const float* __restrict__ vbn,
    float* __restrict__ clam)
{
    const int b   = blockIdx.x >> 3;
    const int m0  = (blockIdx.x & 7) * 128;
    const int tid = threadIdx.x;
    const int vd  = tid & 63;
    const int kq  = tid >> 6;
    float acc[4] = {0.f, 0.f, 0.f, 0.f};
    for (int mi = 0; mi < 128; mi++) {
        const int m = m0 + mi;
        const float vvv = vbn[(b * M_ + m) * DV + vd];
#pragma unroll
        for (int j = 0; j < 4; j++)
            acc[j] = fmaf(ksm[(b * DK + kq + 4 * j) * M_ + m], vvv, acc[j]);
    }
#pragma unroll
    for (int j = 0; j < 4; j++)
        atomicAdd(&clam[(b * DK + kq + 4 * j) * DV + vd], acc[j]);
}

// ---------------- Kernel 4: fused 7x7 conv (pos_lam) + final matmul --------
// ROUND-9 VERSION VERBATIM (65 us proven: VGPR 128, FETCH 14MB, WRITE 33MB).
__global__ __launch_bounds__(512) void k_fuse(
    const float* __restrict__ vbn, const float* __restrict__ qbn,
    const float* __restrict__ clam,
    const float* __restrict__ lw, const float* __restrict__ lb,
    float* __restrict__ out)
{
    __shared__ float v_s[10 * 32 * 64];    // 80 KB: global rows h0-3 .. h0+6
    __shared__ float ostage[64][260];      // 66.6 KB; stride%4==0 -> b128 ok
    __shared__ float lw_t[49 * 16];        // 3.1 KB, [tap][k] (transposed)
    __shared__ float cl_s[16 * 64];        // 4 KB
    __shared__ float lb_s[16];

    const int b   = blockIdx.x >> 3;
    const int rt  = blockIdx.x & 7;
    const int h0  = rt * 4;
    const int tid = threadIdx.x;

    for (int i4 = tid; i4 < 5120; i4 += 512) {   // 20480 floats as float4
        int r   = i4 >> 9;                 // staged row 0..9 = global h0-3+r
        int rem = (i4 & 511) * 4;
        int gr  = h0 - 3 + r;
        float4 val = make_float4(0.f, 0.f, 0.f, 0.f);
        if (gr >= 0 && gr < H_)
            val = *reinterpret_cast<const float4*>(&vbn[(b * M_ + gr * W_) * DV + rem]);
        *reinterpret_cast<float4*>(&v_s[r * 2048 + rem]) = val;
    }
    for (int i = tid; i < 784; i += 512) {       // transpose: [k][tap]->[tap][k]
        int tap = i >> 4, k = i & 15;
        lw_t[i] = lw[k * 49 + tap];
    }
    if (tid < 256)
        *reinterpret_cast<float4*>(&cl_s[tid * 4]) =
            *reinterpret_cast<const float4*>(&clam[b * DK * DV + tid * 4]);
    if (tid < 16) lb_s[tid] = lb[tid];
    __syncthreads();

    const int vd  = tid & 63;
    const int pg  = tid >> 6;       // wave index: pixel column group
    const int px0 = pg * 4;

    for (int grp = 0; grp < 4; grp++) {     // grp = pixel row within tile
        float plam[4][16];
#pragma unroll
        for (int ip = 0; ip < 4; ip++)
#pragma unroll
            for (int k = 0; k < 16; k++) plam[ip][k] = 0.f;

#pragma unroll 1
        for (int dy = 0; dy < 7; dy++) {
            const int rbase = (grp + dy) * W_;   // staged row index * 32
            float vr[10];                        // cols px0-3 .. px0+6
#pragma unroll
            for (int j = 0; j < 10; j++) {
                const int col = px0 - 3 + j;     // wave-uniform validity
                vr[j] = (col >= 0 && col < W_) ? v_s[(rbase + col) * DV + vd] : 0.f;
            }
#pragma unroll
            for (int dx = 0; dx < 7; dx++) {
                const float* lwp = &lw_t[(dy * 7 + dx) * 16];
                float4 l0 = *reinterpret_cast<const float4*>(lwp);
                float4 l1 = *reinterpret_cast<const float4*>(lwp + 4);
                float4 l2 = *reinterpret_cast<const float4*>(lwp + 8);
                float4 l3 = *reinterpret_cast<const float4*>(lwp + 12);
                const float lwv[16] = {l0.x, l0.y, l0.z, l0.w, l1.x, l1.y, l1.z, l1.w,
                                       l2.x, l2.y, l2.z, l2.w, l3.x, l3.y, l3.z, l3.w};
#pragma unroll
                for (int ip = 0; ip < 4; ip++) {
                    const float vvv = vr[ip + dx];
#pragma unroll
                    for (int k = 0; k < 16; k++)
                        plam[ip][k] = fmaf(vvv, lwv[k], plam[ip][k]);
                }
            }
        }
        // epilogue: 4 pixels of this group
#pragma unroll
        for (int ip = 0; ip < 4; ip++) {
            const int p = grp * 32 + px0 + ip;     // 0..127 within tile
            const int m = h0 * W_ + p;
            float lamv[16];
#pragma unroll
            for (int k = 0; k < 16; k++)
                lamv[k] = plam[ip][k] + cl_s[k * DV + vd] + lb_s[k];
            const float* qp = qbn + (size_t)(b * M_ + m) * NH * DK;
            float4 ov;
            float* ovp = reinterpret_cast<float*>(&ov);
#pragma unroll
            for (int n = 0; n < 4; n++) {
                const float4* q4 = reinterpret_cast<const float4*>(qp + n * DK);
                float4 qa = q4[0], qb4 = q4[1], qc = q4[2], qd = q4[3];
                ovp[n] = qa.x * lamv[0] + qa.y * lamv[1] + qa.z * lamv[2] + qa.w * lamv[3]
                       + qb4.x * lamv[4] + qb4.y * lamv[5] + qb4.z * lamv[6] + qb4.w * lamv[7]
                       + qc.x * lamv[8] + qc.y * lamv[9] + qc.z * lamv[10] + qc.w * lamv[11]
                       + qd.x * lamv[12] + qd.y * lamv[13] + qd.z * lamv[14] + qd.w * lamv[15];
            }
            *reinterpret_cast<float4*>(&ostage[vd][(p & 63) * 4]) = ov;
        }
        if (grp & 1) {                      // flush 64 pixels, coalesced
            __syncthreads();
            const int half = grp >> 1;
            const int mb4 = (h0 + half * 2) * W_ * 4;
            for (int i = tid; i < 4096; i += 512) {
                const int vdw  = i >> 6;
                const int off4 = (i & 63) * 4;
                float4 val = *reinterpret_cast<const float4*>(&ostage[vdw][off4]);
                *reinterpret_cast<float4*>(
                    out + (size_t)b * (C_ * M_) + (size_t)vdw * 4096 + mb4 + off4) = val;
            }
            __syncthreads();
        }
    }
}

extern "C" void kernel_launch(void* const* d_in, const int* in_sizes, int n_in,
                              void* d_out, int out_size, void* d_ws, size_t ws_size,
                              hipStream_t stream)
{
    (void)in_sizes; (void)n_in; (void)out_size; (void)ws_size;
    const float* x   = (const float*)d_in[0];
    const float* w   = (const float*)d_in[1];
    const float* qg  = (const float*)d_in[2];
    const float* qb  = (const float*)d_in[3];
    const float* qm  = (const float*)d_in[4];
    const float* qvr = (const float*)d_in[5];
    const float* vg  = (const float*)d_in[6];
    const float* vb  = (const float*)d_in[7];
    const float* vm  = (const float*)d_in[8];
    const float* vvr = (const float*)d_in[9];
    const float* lw  = (const float*)d_in[10];
    const float* lb  = (const float*)d_in[11];
    float* out = (float*)d_out;

    float* ws   = (float*)d_ws;
    float* q_bn = ws;                  // [b][m][n][k]  2,097,152 f
    float* v_bn = ws + 2097152;        // [b][m][vd]    2,097,152 f
    float* k_bf = ws + 4194304;        // [b][k][m]       524,288 f (in-place sm)
    float* clam = ws + 4718592;        // [b][k][vd]       32,768 f
    __bf16* wbf = (__bf16*)(ws + 4751360);   // 36,864 bf16 (73,728 B)

    hipMemsetAsync(clam, 0, 32768 * sizeof(float), stream);
    hipLaunchKernelGGL(k_wbf, dim3(36), dim3(256), 0, stream, w, wbf);
    hipLaunchKernelGGL(k_qkv, dim3(512), dim3(256), 0, stream,
                       x, wbf, qg, qb, qm, qvr, vg, vb, vm, vvr, q_bn, k_bf, v_bn);
    hipLaunchKernelGGL(k_softmax, dim3(512), dim3(256), 0, stream, k_bf);
    hipLaunchKernelGGL(k_clam, dim3(256), dim3(256), 0, stream, k_bf, v_bn, clam);
    hipLaunchKernelGGL(k_fuse, dim3(256), dim3(512), 0, stream,
                       v_bn, q_bn, clam, lw, lb, out);
}